// Round 3
// baseline (263.139 us; speedup 1.0000x reference)
//
#include <hip/hip_runtime.h>

// Problem constants: N=64, A=5, C=20, FM=52, M=32
#define N_IMG 64
#define NA 5
#define NC 20
#define FM 52
#define NM 32
#define FMFM (FM * FM)                  // 2704 (divisible by 4)
#define Q (FMFM / 4)                    // 676 float4 per channel plane
#define CELLS_PER_IMG (NA * FMFM)       // 13520
#define T_PER_IMG (CELLS_PER_IMG / 4)   // 3380 threads per image (4 cells each)
#define BLOCK 256
#define BX ((T_PER_IMG + BLOCK - 1) / BLOCK)  // 14

__device__ __forceinline__ float fast_rcp(float x) { return __builtin_amdgcn_rcpf(x); }

__device__ __forceinline__ float sl1(float a, float b) {
    float d = a - b;
    float ad = fabsf(d);
    return ad < 1.0f ? 0.5f * d * d : ad - 0.5f;
}

__device__ __forceinline__ void ld4(const float4* p, float o[4]) {
    float4 v = *p;
    o[0] = v.x; o[1] = v.y; o[2] = v.z; o[3] = v.w;
}

__global__ __launch_bounds__(BLOCK, 3) void yolo_loss_main(
    const float* __restrict__ preds,     // [N, A*25, FM, FM]
    const float* __restrict__ loc_t,     // [N, A, 4, FM, FM]
    const float* __restrict__ cls_t,     // [N, A, C, FM, FM]
    const float* __restrict__ box_t,     // [N, M, 4] xyxy
    const float* __restrict__ anchors,   // [A, 2]
    double* __restrict__ acc)            // acc[0]=loss sum, acc[1]=num_pos
{
    __shared__ __align__(16) float sbox[NM * 4];
    __shared__ float sarea[NM];
    __shared__ double wsum[BLOCK / 64];
    __shared__ double wpos[BLOCK / 64];

    const int n = blockIdx.y;
    const int tid = threadIdx.x;

    if (tid < NM * 4) sbox[tid] = box_t[n * NM * 4 + tid];
    __syncthreads();
    if (tid < NM) {
        float x1 = sbox[tid * 4 + 0], y1 = sbox[tid * 4 + 1];
        float x2 = sbox[tid * 4 + 2], y2 = sbox[tid * 4 + 3];
        sarea[tid] = (x2 - x1) * (y2 - y1);
    }
    __syncthreads();

    const int t = blockIdx.x * BLOCK + tid;
    float loss = 0.0f;
    float posn = 0.0f;

    if (t < T_PER_IMG) {
        const int g = t * 4;                 // first of 4 consecutive cells
        const int a = g / FMFM;
        const int rem = g - a * FMFM;        // y*FM + x, x multiple of 4
        const int yy = rem / FM;
        const int xx = rem - yy * FM;

        const float4* pb = (const float4*)(preds + (size_t)(n * NA + a) * 25 * FMFM + rem);
        const float4* cb = (const float4*)(cls_t + (size_t)(n * NA + a) * NC * FMFM + rem);
        const float4* lb = (const float4*)(loc_t + (size_t)(n * NA + a) * 4  * FMFM + rem);

        // ---- Pass 1: class logits into registers; per-cell max ----
        float l[NC][4];
        #pragma unroll
        for (int c = 0; c < NC; ++c) ld4(pb + (5 + c) * Q, l[c]);

        float m[4] = { l[0][0], l[0][1], l[0][2], l[0][3] };
        #pragma unroll
        for (int c = 1; c < NC; ++c) {
            #pragma unroll
            for (int j = 0; j < 4; ++j) m[j] = fmaxf(m[j], l[c][j]);
        }

        // ---- Pass 2: stream cls targets (max for pos) + exp-sum; l <- exp(l-m) ----
        float cmax[4] = {0.f, 0.f, 0.f, 0.f};
        float s[4] = {0.f, 0.f, 0.f, 0.f};
        #pragma unroll
        for (int c = 0; c < NC; ++c) {
            float tv[4]; ld4(cb + c * Q, tv);
            #pragma unroll
            for (int j = 0; j < 4; ++j) {
                cmax[j] = fmaxf(cmax[j], tv[j]);
                float e = __expf(l[c][j] - m[j]);
                s[j] += e;
                l[c][j] = e;                 // overwrite logit with its exp
            }
        }

        float posf[4], iouw[4];
        #pragma unroll
        for (int j = 0; j < 4; ++j) {
            bool p = cmax[j] > 0.0f;
            posf[j] = p ? 1.0f : 0.0f;
            iouw[j] = p ? 1.0f : 0.1f;
            posn += posf[j];
        }

        // ---- Head channels + loc targets ----
        float P0[4], P1[4], P2[4], P3[4], P4[4], T0[4], T1[4], T2[4], T3[4];
        ld4(pb + 0 * Q, P0); ld4(pb + 1 * Q, P1); ld4(pb + 2 * Q, P2);
        ld4(pb + 3 * Q, P3); ld4(pb + 4 * Q, P4);
        ld4(lb + 0 * Q, T0); ld4(lb + 1 * Q, T1);
        ld4(lb + 2 * Q, T2); ld4(lb + 3 * Q, T3);

        const float aw = anchors[a * 2 + 0];
        const float ah = anchors[a * 2 + 1];

        float px1[4], py1[4], px2[4], py2[4], ap[4], ib[4], db[4];
        #pragma unroll
        for (int j = 0; j < 4; ++j) {
            float sx = fast_rcp(1.0f + __expf(-P0[j]));
            float sy = fast_rcp(1.0f + __expf(-P1[j]));
            float ew = __expf(P2[j]);
            float eh = __expf(P3[j]);
            // loc loss, mask multiplies the smooth_l1 result
            loss += posf[j] * (sl1(sx, T0[j]) + sl1(sy, T1[j]) +
                               sl1(ew, T2[j]) + sl1(eh, T3[j]));
            float bx = sx + (float)(xx + j);
            float by = sy + (float)yy;
            float bw = aw * ew, bh = ah * eh;
            px1[j] = bx - 0.5f * bw; py1[j] = by - 0.5f * bh;
            px2[j] = bx + 0.5f * bw; py2[j] = by + 0.5f * bh;
            ap[j] = (px2[j] - px1[j]) * (py2[j] - py1[j]);
            ib[j] = 0.0f; db[j] = 1.0f;   // best iou as fraction ib/db
        }

        // ---- IoU argmax over 32 boxes, division-free (cross-mult compare) ----
        #pragma unroll 4
        for (int tb = 0; tb < NM; ++tb) {
            float b0 = sbox[tb * 4 + 0], b1 = sbox[tb * 4 + 1];
            float b2 = sbox[tb * 4 + 2], b3 = sbox[tb * 4 + 3];
            float sa = sarea[tb];
            #pragma unroll
            for (int j = 0; j < 4; ++j) {
                float lx = fmaxf(px1[j], b0), ly = fmaxf(py1[j], b1);
                float rx = fminf(px2[j], b2), ry = fminf(py2[j], b3);
                float w = fmaxf(rx - lx, 0.0f), h = fmaxf(ry - ly, 0.0f);
                float inter = w * h;
                float den = ap[j] + sa - inter;   // > 0 always (den >= max area)
                bool gt = inter * db[j] > ib[j] * den;
                ib[j] = gt ? inter : ib[j];
                db[j] = gt ? den   : db[j];
            }
        }

        #pragma unroll
        for (int j = 0; j < 4; ++j) {
            float best = ib[j] * fast_rcp(db[j]);
            float ip = fast_rcp(1.0f + __expf(-P4[j]));
            loss += sl1(ip * iouw[j], best * iouw[j]);
        }

        // ---- Pass 3: cls loss (re-read ct, L2/L3-hot; l already holds exp) ----
        float inv[4];
        #pragma unroll
        for (int j = 0; j < 4; ++j) inv[j] = fast_rcp(s[j]);
        #pragma unroll
        for (int c = 0; c < NC; ++c) {
            float tv[4]; ld4(cb + c * Q, tv);
            #pragma unroll
            for (int j = 0; j < 4; ++j) {
                float v = sl1(l[c][j] * inv[j], tv[j]);
                loss += tv[j] > 0.0f ? v : 0.0f;
            }
        }
    }

    // ---- Reduction: wave shfl (double) -> LDS -> one atomic per block ----
    double dl = (double)loss;
    double dp = (double)posn;
    #pragma unroll
    for (int off = 32; off > 0; off >>= 1) {
        dl += __shfl_down(dl, off);
        dp += __shfl_down(dp, off);
    }
    const int wave = tid >> 6, lane = tid & 63;
    if (lane == 0) { wsum[wave] = dl; wpos[wave] = dp; }
    __syncthreads();
    if (tid == 0) {
        double tl = 0.0, tp = 0.0;
        #pragma unroll
        for (int w = 0; w < BLOCK / 64; ++w) { tl += wsum[w]; tp += wpos[w]; }
        atomicAdd(&acc[0], tl);
        atomicAdd(&acc[1], tp);
    }
}

__global__ void yolo_loss_finalize(const double* __restrict__ acc,
                                   float* __restrict__ out) {
    out[0] = (float)(acc[0] / acc[1]);
}

extern "C" void kernel_launch(void* const* d_in, const int* in_sizes, int n_in,
                              void* d_out, int out_size, void* d_ws, size_t ws_size,
                              hipStream_t stream) {
    const float* preds   = (const float*)d_in[0];
    const float* loc_t   = (const float*)d_in[1];
    const float* cls_t   = (const float*)d_in[2];
    const float* box_t   = (const float*)d_in[3];
    const float* anchors = (const float*)d_in[4];
    double* acc = (double*)d_ws;

    hipMemsetAsync(d_ws, 0, 2 * sizeof(double), stream);

    dim3 grid(BX, N_IMG);
    yolo_loss_main<<<grid, BLOCK, 0, stream>>>(preds, loc_t, cls_t, box_t,
                                               anchors, acc);
    yolo_loss_finalize<<<1, 1, 0, stream>>>(acc, (float*)d_out);
}

// Round 5
// 260.301 us; speedup vs baseline: 1.0109x; 1.0109x over previous
//
#include <hip/hip_runtime.h>

// Problem constants: N=64, A=5, C=20, FM=52, M=32
#define N_IMG 64
#define NA 5
#define NC 20
#define FM 52
#define NM 32
#define FMFM (FM * FM)                  // 2704 (div by 4)
#define Q (FMFM / 4)                    // 676 float4 per channel plane
#define CELLS (NA * FMFM)               // 13520
#define TPI (CELLS / 4)                 // 3380 threads/image, 4 cells each
#define BLOCK 256
#define BX ((TPI + BLOCK - 1) / BLOCK)  // 14

__device__ __forceinline__ float frcp(float x) { return __builtin_amdgcn_rcpf(x); }
__device__ __forceinline__ float sl1(float a, float b) {
    float d = a - b;
    float ad = fabsf(d);
    return ad < 1.0f ? 0.5f * d * d : ad - 0.5f;
}

// Per-component macros (C = .x/.y/.z/.w component, JX = lane offset 0..3).
#define HEADJ(C, JX) {                                                        \
    float sx = frcp(1.0f + __expf(-P0.C));                                    \
    float sy = frcp(1.0f + __expf(-P1.C));                                    \
    float ew = __expf(P2.C);                                                  \
    float eh = __expf(P3.C);                                                  \
    loss += pos.C * (sl1(sx, T0.C) + sl1(sy, T1.C) +                          \
                     sl1(ew, T2.C) + sl1(eh, T3.C));                          \
    float bx = sx + (float)(xx + JX);                                         \
    float by = sy + (float)yy;                                                \
    float bw = aw * ew, bh = ah * eh;                                         \
    px1.C = bx - 0.5f * bw; py1.C = by - 0.5f * bh;                           \
    px2.C = bx + 0.5f * bw; py2.C = by + 0.5f * bh;                           \
    ap.C = (px2.C - px1.C) * (py2.C - py1.C);                                 \
}

#define IOUJ(C) {                                                             \
    float lx = fmaxf(px1.C, B.x), ly = fmaxf(py1.C, B.y);                     \
    float rx = fminf(px2.C, B.z), ry = fminf(py2.C, B.w);                     \
    float w_ = fmaxf(rx - lx, 0.0f), h_ = fmaxf(ry - ly, 0.0f);               \
    float it = w_ * h_;                                                       \
    float dn = ap.C + sa - it;                                                \
    bool gt = it * db.C > ib.C * dn;                                          \
    ib.C = gt ? it : ib.C;                                                    \
    db.C = gt ? dn : db.C;                                                    \
}

#define IOULOSSJ(C) {                                                         \
    float best  = ib.C * frcp(db.C);                                          \
    float ipred = frcp(1.0f + __expf(-P4.C));                                 \
    loss += sl1(ipred * wgt.C, best * wgt.C);                                 \
}

__global__ __launch_bounds__(BLOCK, 4) void yolo_loss_main(
    const float* __restrict__ preds,     // [N, A*25, FM, FM]
    const float* __restrict__ loc_t,     // [N, A, 4, FM, FM]
    const float* __restrict__ cls_t,     // [N, A, C, FM, FM]
    const float4* __restrict__ box_t,    // [N, M] xyxy
    const float* __restrict__ anchors,   // [A, 2]
    double* __restrict__ acc)            // acc[0]=loss sum, acc[1]=num_pos
{
    __shared__ float4 sbox[NM];
    __shared__ float sarea[NM];
    __shared__ double wsum[BLOCK / 64];
    __shared__ double wpos[BLOCK / 64];

    const int n = blockIdx.y;
    const int tid = threadIdx.x;

    if (tid < NM) {
        float4 b = box_t[n * NM + tid];
        sbox[tid] = b;
        sarea[tid] = (b.z - b.x) * (b.w - b.y);
    }
    __syncthreads();

    const int t = blockIdx.x * BLOCK + tid;
    float loss = 0.0f;
    float posn = 0.0f;

    if (t < TPI) {
        const int g   = t * 4;
        const int a   = g / FMFM;
        const int rem = g - a * FMFM;     // y*FM + x, x multiple of 4
        const int yy  = rem / FM;
        const int xx  = rem - yy * FM;
        const int q   = rem >> 2;

        const float4* pb = (const float4*)(preds + (size_t)(n * NA + a) * 25 * FMFM) + q;
        const float4* cb = (const float4*)(cls_t + (size_t)(n * NA + a) * NC * FMFM) + q;
        const float4* lb = (const float4*)(loc_t + (size_t)(n * NA + a) * 4  * FMFM) + q;

        // ---- Phase 1: class logits -> regs; per-cell max; softmax denom.
        // (denominator needs NO targets -> single ct pass below, short l live range)
        float4 l[NC];
        #pragma unroll
        for (int c = 0; c < NC; ++c) l[c] = pb[(5 + c) * Q];

        float4 m = l[0];
        #pragma unroll
        for (int c = 1; c < NC; ++c) {
            m.x = fmaxf(m.x, l[c].x); m.y = fmaxf(m.y, l[c].y);
            m.z = fmaxf(m.z, l[c].z); m.w = fmaxf(m.w, l[c].w);
        }

        float4 s = make_float4(0.f, 0.f, 0.f, 0.f);
        #pragma unroll
        for (int c = 0; c < NC; ++c) {
            s.x += __expf(l[c].x - m.x); s.y += __expf(l[c].y - m.y);
            s.z += __expf(l[c].z - m.z); s.w += __expf(l[c].w - m.w);
        }
        float4 inv;
        inv.x = frcp(s.x); inv.y = frcp(s.y); inv.z = frcp(s.z); inv.w = frcp(s.w);

        // ---- Phase 2: SINGLE cls-target stream: pos-max + fused cls loss.
        float4 cmax = make_float4(0.f, 0.f, 0.f, 0.f);
        #pragma unroll
        for (int c = 0; c < NC; ++c) {
            float4 tv = cb[c * Q];
            cmax.x = fmaxf(cmax.x, tv.x); cmax.y = fmaxf(cmax.y, tv.y);
            cmax.z = fmaxf(cmax.z, tv.z); cmax.w = fmaxf(cmax.w, tv.w);
            loss += tv.x > 0.0f ? sl1(__expf(l[c].x - m.x) * inv.x, tv.x) : 0.0f;
            loss += tv.y > 0.0f ? sl1(__expf(l[c].y - m.y) * inv.y, tv.y) : 0.0f;
            loss += tv.z > 0.0f ? sl1(__expf(l[c].z - m.z) * inv.z, tv.z) : 0.0f;
            loss += tv.w > 0.0f ? sl1(__expf(l[c].w - m.w) * inv.w, tv.w) : 0.0f;
        }
        // l is DEAD here. Fence so phase-3 loads can't hoist into the
        // high-pressure region above.
        __builtin_amdgcn_sched_barrier(0);

        float4 pos, wgt;
        pos.x = cmax.x > 0.0f ? 1.0f : 0.0f;  wgt.x = cmax.x > 0.0f ? 1.0f : 0.1f;
        pos.y = cmax.y > 0.0f ? 1.0f : 0.0f;  wgt.y = cmax.y > 0.0f ? 1.0f : 0.1f;
        pos.z = cmax.z > 0.0f ? 1.0f : 0.0f;  wgt.z = cmax.z > 0.0f ? 1.0f : 0.1f;
        pos.w = cmax.w > 0.0f ? 1.0f : 0.0f;  wgt.w = cmax.w > 0.0f ? 1.0f : 0.1f;
        posn = pos.x + pos.y + pos.z + pos.w;

        // ---- Phase 3: head channels + loc targets, loc loss, box decode.
        float4 P0 = pb[0 * Q], P1 = pb[1 * Q], P2 = pb[2 * Q];
        float4 P3 = pb[3 * Q], P4 = pb[4 * Q];
        float4 T0 = lb[0 * Q], T1 = lb[1 * Q], T2 = lb[2 * Q], T3 = lb[3 * Q];

        const float aw = anchors[a * 2 + 0];
        const float ah = anchors[a * 2 + 1];

        float4 px1, py1, px2, py2, ap, ib, db;
        HEADJ(x, 0) HEADJ(y, 1) HEADJ(z, 2) HEADJ(w, 3)
        ib = make_float4(0.f, 0.f, 0.f, 0.f);
        db = make_float4(1.f, 1.f, 1.f, 1.f);

        // ---- Phase 4: IoU argmax over 32 boxes, division-free compare.
        #pragma unroll 4
        for (int tb = 0; tb < NM; ++tb) {
            float4 B = sbox[tb];
            float sa = sarea[tb];
            IOUJ(x) IOUJ(y) IOUJ(z) IOUJ(w)
        }
        IOULOSSJ(x) IOULOSSJ(y) IOULOSSJ(z) IOULOSSJ(w)
    }

    // ---- Reduction: wave shfl (double) -> LDS -> one atomic per block ----
    double dl = (double)loss;
    double dp = (double)posn;
    #pragma unroll
    for (int off = 32; off > 0; off >>= 1) {
        dl += __shfl_down(dl, off);
        dp += __shfl_down(dp, off);
    }
    const int wave = tid >> 6, lane = tid & 63;
    if (lane == 0) { wsum[wave] = dl; wpos[wave] = dp; }
    __syncthreads();
    if (tid == 0) {
        double tl = 0.0, tp = 0.0;
        #pragma unroll
        for (int w = 0; w < BLOCK / 64; ++w) { tl += wsum[w]; tp += wpos[w]; }
        atomicAdd(&acc[0], tl);
        atomicAdd(&acc[1], tp);
    }
}

__global__ void yolo_loss_finalize(const double* __restrict__ acc,
                                   float* __restrict__ out) {
    out[0] = (float)(acc[0] / acc[1]);
}

extern "C" void kernel_launch(void* const* d_in, const int* in_sizes, int n_in,
                              void* d_out, int out_size, void* d_ws, size_t ws_size,
                              hipStream_t stream) {
    const float*  preds   = (const float*)d_in[0];
    const float*  loc_t   = (const float*)d_in[1];
    const float*  cls_t   = (const float*)d_in[2];
    const float4* box_t   = (const float4*)d_in[3];
    const float*  anchors = (const float*)d_in[4];
    double* acc = (double*)d_ws;

    hipMemsetAsync(d_ws, 0, 2 * sizeof(double), stream);

    dim3 grid(BX, N_IMG);
    yolo_loss_main<<<grid, BLOCK, 0, stream>>>(preds, loc_t, cls_t, box_t,
                                               anchors, acc);
    yolo_loss_finalize<<<1, 1, 0, stream>>>(acc, (float*)d_out);
}

// Round 6
// 209.836 us; speedup vs baseline: 1.2540x; 1.2405x over previous
//
#include <hip/hip_runtime.h>

// Problem constants: N=64, A=5, C=20, FM=52, M=32
#define N_IMG 64
#define NA 5
#define NC 20
#define FM 52
#define NM 32
#define FMFM (FM * FM)                  // 2704 (div by 4)
#define Q (FMFM / 4)                    // 676 float4 per channel plane
#define CELLS (NA * FMFM)               // 13520
#define TPI (CELLS / 4)                 // 3380 threads/image, 4 cells each
#define BLOCK 256
#define BX ((TPI + BLOCK - 1) / BLOCK)  // 14

__device__ __forceinline__ float frcp(float x) { return __builtin_amdgcn_rcpf(x); }
__device__ __forceinline__ float sl1(float a, float b) {
    float d = a - b;
    float ad = fabsf(d);
    return ad < 1.0f ? 0.5f * d * d : ad - 0.5f;
}

// Online softmax update (running max m, running denom s), component C.
#define ONL(C) { float mn = fmaxf(m.C, v.C);                                  \
    s.C = s.C * __expf(m.C - mn) + __expf(v.C - mn); m.C = mn; }

// Fused cls-target pass: positivity max + masked smooth-l1 on softmax prob.
#define CLSJ(C) {                                                             \
    cmax.C = fmaxf(cmax.C, tv.C);                                             \
    float pr = __expf(lv.C - m.C) * inv.C;                                    \
    lacc.C += tv.C > 0.0f ? sl1(pr, tv.C) : 0.0f; }

#define HEADJ(C, JX) {                                                        \
    float sx = frcp(1.0f + __expf(-P0.C));                                    \
    float sy = frcp(1.0f + __expf(-P1.C));                                    \
    float ew = __expf(P2.C);                                                  \
    float eh = __expf(P3.C);                                                  \
    lacc.C += pos.C * (sl1(sx, T0.C) + sl1(sy, T1.C) +                        \
                       sl1(ew, T2.C) + sl1(eh, T3.C));                        \
    float bx = sx + (float)(xx + JX);                                         \
    float by = sy + (float)yy;                                                \
    float bw = aw * ew, bh = ah * eh;                                         \
    px1.C = bx - 0.5f * bw; py1.C = by - 0.5f * bh;                           \
    px2.C = bx + 0.5f * bw; py2.C = by + 0.5f * bh;                           \
    ap.C  = (px2.C - px1.C) * (py2.C - py1.C); }

#define IOUJ(C) {                                                             \
    float lx = fmaxf(px1.C, B.x), ly = fmaxf(py1.C, B.y);                     \
    float rx = fminf(px2.C, B.z), ry = fminf(py2.C, B.w);                     \
    float w_ = fmaxf(rx - lx, 0.0f), h_ = fmaxf(ry - ly, 0.0f);               \
    float it = w_ * h_;                                                       \
    float dn = ap.C + sa - it;                                                \
    bool gt = it * db.C > ib.C * dn;                                          \
    ib.C = gt ? it : ib.C;                                                    \
    db.C = gt ? dn : db.C; }

#define IOULOSSJ(C) {                                                         \
    float best  = ib.C * frcp(db.C);                                          \
    float ipred = frcp(1.0f + __expf(-P4.C));                                 \
    lacc.C += sl1(ipred * wgt.C, best * wgt.C); }

__global__ __launch_bounds__(BLOCK) void yolo_loss_main(
    const float* __restrict__ preds,     // [N, A*25, FM, FM]
    const float* __restrict__ loc_t,     // [N, A, 4, FM, FM]
    const float* __restrict__ cls_t,     // [N, A, C, FM, FM]
    const float4* __restrict__ box_t,    // [N, M] xyxy
    const float* __restrict__ anchors,   // [A, 2]
    double* __restrict__ acc)            // acc[0]=loss sum, acc[1]=num_pos
{
    __shared__ float4 sbox[NM];
    __shared__ float sarea[NM];
    __shared__ double wsum[BLOCK / 64];
    __shared__ double wpos[BLOCK / 64];

    const int n = blockIdx.y;
    const int tid = threadIdx.x;

    if (tid < NM) {
        float4 b = box_t[n * NM + tid];
        sbox[tid] = b;
        sarea[tid] = (b.z - b.x) * (b.w - b.y);
    }
    __syncthreads();

    const int t = blockIdx.x * BLOCK + tid;
    float loss = 0.0f, posn = 0.0f;

    if (t < TPI) {
        const int g   = t * 4;
        const int a   = g / FMFM;
        const int rem = g - a * FMFM;     // y*FM + x, x multiple of 4
        const int yy  = rem / FM;
        const int xx  = rem - yy * FM;
        const int q   = rem >> 2;

        const float4* pb = (const float4*)(preds + (size_t)(n * NA + a) * 25 * FMFM) + q;
        const float4* cb = (const float4*)(cls_t + (size_t)(n * NA + a) * NC * FMFM) + q;
        const float4* lb = (const float4*)(loc_t + (size_t)(n * NA + a) * 4  * FMFM) + q;

        float4 lacc = make_float4(0.f, 0.f, 0.f, 0.f);

        // ---- Pass 1: ONLINE softmax max+denominator over 20 logit planes.
        // Only m,s live (8 regs) -- no 20-float4 array, nothing to spill.
        float4 m = make_float4(-1e30f, -1e30f, -1e30f, -1e30f);
        float4 s = make_float4(0.f, 0.f, 0.f, 0.f);
        #pragma unroll 5
        for (int c = 0; c < NC; ++c) {
            float4 v = pb[(5 + c) * Q];
            ONL(x) ONL(y) ONL(z) ONL(w)
        }
        float4 inv;
        inv.x = frcp(s.x); inv.y = frcp(s.y); inv.z = frcp(s.z); inv.w = frcp(s.w);

        // Opaque alias of pb: forces pass-2 logit RE-LOADS (L2/L3-hot) so the
        // compiler cannot CSE them against pass 1 and keep 80 VGPRs alive.
        const float4* pb2 = pb;
        asm volatile("" : "+v"(pb2));

        // ---- Pass 2: re-read logits + stream cls targets: pos + cls loss.
        float4 cmax = make_float4(0.f, 0.f, 0.f, 0.f);
        #pragma unroll 4
        for (int c = 0; c < NC; ++c) {
            float4 lv = pb2[(5 + c) * Q];
            float4 tv = cb[c * Q];
            CLSJ(x) CLSJ(y) CLSJ(z) CLSJ(w)
        }

        float4 pos, wgt;
        pos.x = cmax.x > 0.f ? 1.f : 0.f;  wgt.x = cmax.x > 0.f ? 1.f : 0.1f;
        pos.y = cmax.y > 0.f ? 1.f : 0.f;  wgt.y = cmax.y > 0.f ? 1.f : 0.1f;
        pos.z = cmax.z > 0.f ? 1.f : 0.f;  wgt.z = cmax.z > 0.f ? 1.f : 0.1f;
        pos.w = cmax.w > 0.f ? 1.f : 0.f;  wgt.w = cmax.w > 0.f ? 1.f : 0.1f;
        posn = pos.x + pos.y + pos.z + pos.w;

        // ---- Phase 3: head channels + loc targets, loc loss, box decode.
        float4 P0 = pb[0 * Q], P1 = pb[1 * Q], P2 = pb[2 * Q];
        float4 P3 = pb[3 * Q], P4 = pb[4 * Q];
        float4 T0 = lb[0 * Q], T1 = lb[1 * Q], T2 = lb[2 * Q], T3 = lb[3 * Q];

        const float aw = anchors[a * 2 + 0];
        const float ah = anchors[a * 2 + 1];

        float4 px1, py1, px2, py2, ap, ib, db;
        HEADJ(x, 0) HEADJ(y, 1) HEADJ(z, 2) HEADJ(w, 3)
        ib = make_float4(0.f, 0.f, 0.f, 0.f);
        db = make_float4(1.f, 1.f, 1.f, 1.f);

        // ---- Phase 4: IoU argmax over 32 boxes, division-free compare.
        #pragma unroll 4
        for (int tb = 0; tb < NM; ++tb) {
            float4 B = sbox[tb];
            float sa = sarea[tb];
            IOUJ(x) IOUJ(y) IOUJ(z) IOUJ(w)
        }
        IOULOSSJ(x) IOULOSSJ(y) IOULOSSJ(z) IOULOSSJ(w)

        loss = lacc.x + lacc.y + lacc.z + lacc.w;
    }

    // ---- Reduction: wave shfl (double) -> LDS -> one atomic per block ----
    double dl = (double)loss;
    double dp = (double)posn;
    #pragma unroll
    for (int off = 32; off > 0; off >>= 1) {
        dl += __shfl_down(dl, off);
        dp += __shfl_down(dp, off);
    }
    const int wave = tid >> 6, lane = tid & 63;
    if (lane == 0) { wsum[wave] = dl; wpos[wave] = dp; }
    __syncthreads();
    if (tid == 0) {
        double tl = 0.0, tp = 0.0;
        #pragma unroll
        for (int w = 0; w < BLOCK / 64; ++w) { tl += wsum[w]; tp += wpos[w]; }
        atomicAdd(&acc[0], tl);
        atomicAdd(&acc[1], tp);
    }
}

__global__ void yolo_loss_finalize(const double* __restrict__ acc,
                                   float* __restrict__ out) {
    out[0] = (float)(acc[0] / acc[1]);
}

extern "C" void kernel_launch(void* const* d_in, const int* in_sizes, int n_in,
                              void* d_out, int out_size, void* d_ws, size_t ws_size,
                              hipStream_t stream) {
    const float*  preds   = (const float*)d_in[0];
    const float*  loc_t   = (const float*)d_in[1];
    const float*  cls_t   = (const float*)d_in[2];
    const float4* box_t   = (const float4*)d_in[3];
    const float*  anchors = (const float*)d_in[4];
    double* acc = (double*)d_ws;

    hipMemsetAsync(d_ws, 0, 2 * sizeof(double), stream);

    dim3 grid(BX, N_IMG);
    yolo_loss_main<<<grid, BLOCK, 0, stream>>>(preds, loc_t, cls_t, box_t,
                                               anchors, acc);
    yolo_loss_finalize<<<1, 1, 0, stream>>>(acc, (float*)d_out);
}